// Round 1
// baseline (1092.118 us; speedup 1.0000x reference)
//
#include <hip/hip_runtime.h>

#define T_LEN 131072
#define RD 32
#define SD 512
#define QD 256
#define NL 27
#define KTOT (NL * RD)   // 864

typedef __attribute__((ext_vector_type(8))) short short8;
typedef __attribute__((ext_vector_type(4))) float floatx4;

__device__ __forceinline__ unsigned short f2bf(float f) {
    union { float f; unsigned int i; } v; v.f = f;
    unsigned int r = v.i + 0x7fffu + ((v.i >> 16) & 1u);  // RNE
    return (unsigned short)(r >> 16);
}

__device__ __forceinline__ void gload_lds16(const void* g, void* l) {
    __builtin_amdgcn_global_load_lds(
        (const __attribute__((address_space(1))) unsigned int*)g,
        (__attribute__((address_space(3))) unsigned int*)l, 16, 0, 0);
}

// ---------------- initial conv: [1,T] -> [T][32] fp32 + bf16 copies ----------------
__global__ __launch_bounds__(256)
void k_conv_init(const float* __restrict__ x, const float* __restrict__ Wc,
                 const float* __restrict__ bc, float* __restrict__ xout,
                 unsigned short* __restrict__ xoutb)
{
    const int t = blockIdx.x * 256 + threadIdx.x;
    const float xm = (t > 0) ? x[t - 1] : 0.f;
    const float x0 = x[t];
    const float xp = (t < T_LEN - 1) ? x[t + 1] : 0.f;
    float* row = xout + (size_t)t * RD;
    unsigned short* rowb = xoutb + (size_t)t * RD;
#pragma unroll
    for (int o = 0; o < RD; ++o) {
        const float v = bc[o] + Wc[o * 3 + 0] * xm + Wc[o * 3 + 1] * x0 + Wc[o * 3 + 2] * xp;
        row[o] = v;
        rowb[o] = f2bf(v);
    }
}

// ---------------- weight prep ----------------
__global__ __launch_bounds__(256)
void k_wprep(const float* __restrict__ Wt, const float* __restrict__ Ws,
             const float* __restrict__ Wd,
             unsigned short* __restrict__ Wg, unsigned short* __restrict__ Wdb)
{
    const int idx = blockIdx.x * 256 + threadIdx.x;
    const int n1 = NL * 64 * 96;
    const int n2 = NL * RD * RD;
    if (idx < n1) {
        const int l = idx / (64 * 96);
        const int rem = idx % (64 * 96);
        const int m = rem / 96;
        const int k = rem % 96;
        const int j = k / 32;
        const int c = k % 32;
        float v;
        if (m < 32) v = Wt[(((size_t)l * RD + m) * RD + c) * 3 + j];
        else        v = Ws[(((size_t)l * RD + (m - 32)) * RD + c) * 3 + j];
        Wg[idx] = f2bf(v);
    } else if (idx < n1 + n2) {
        const int i2 = idx - n1;
        Wdb[i2] = f2bf(Wd[i2]);
    }
}

// ---------------- one residual layer via MFMA, 128 t per block ----------------
__global__ __launch_bounds__(256)
void k_layer_mfma(const float* __restrict__ xin, const unsigned short* __restrict__ xinb,
                  float* __restrict__ xout, unsigned short* __restrict__ xoutb,
                  unsigned short* __restrict__ Gt,
                  const unsigned short* __restrict__ Wg,   // [64][96] bf16
                  const unsigned short* __restrict__ Wdb,  // [32][32] bf16
                  const float* __restrict__ bt, const float* __restrict__ bs,
                  const float* __restrict__ bd, int d, int layer)
{
    __shared__ unsigned short gtile[128 * 32];  // 8 KB
    const int tid = threadIdx.x;
    const int lane = tid & 63;
    const int w = tid >> 6;
    const int quad = lane >> 4;
    const int l16 = lane & 15;
    const int tbase = blockIdx.x * 128 + w * 32;

    short8 afr[3][4];
#pragma unroll
    for (int j = 0; j < 3; ++j)
#pragma unroll
        for (int mt = 0; mt < 4; ++mt)
            afr[j][mt] = *reinterpret_cast<const short8*>(
                Wg + (size_t)(mt * 16 + l16) * 96 + j * 32 + quad * 8);

    floatx4 acc[4][2];
    const floatx4 vzero = {0.f, 0.f, 0.f, 0.f};
#pragma unroll
    for (int mt = 0; mt < 4; ++mt)
#pragma unroll
        for (int nt = 0; nt < 2; ++nt) acc[mt][nt] = vzero;

#pragma unroll
    for (int nt = 0; nt < 2; ++nt) {
        const int t = tbase + nt * 16 + l16;
#pragma unroll
        for (int j = 0; j < 3; ++j) {
            const int tt = t + (j - 1) * d;
            short8 b;
            if (tt >= 0 && tt < T_LEN) {
                b = *reinterpret_cast<const short8*>(xinb + (size_t)tt * RD + quad * 8);
            } else {
#pragma unroll
                for (int i = 0; i < 8; ++i) b[i] = 0;
            }
#pragma unroll
            for (int mt = 0; mt < 4; ++mt)
                acc[mt][nt] = __builtin_amdgcn_mfma_f32_16x16x32_bf16(afr[j][mt], b, acc[mt][nt], 0, 0, 0);
        }
    }

#pragma unroll
    for (int nt = 0; nt < 2; ++nt) {
        const int t = tbase + nt * 16 + l16;
        const int tloc = w * 32 + nt * 16 + l16;
#pragma unroll
        for (int pair = 0; pair < 2; ++pair) {
            const floatx4 bt4 = *reinterpret_cast<const floatx4*>(bt + pair * 16 + quad * 4);
            const floatx4 bs4 = *reinterpret_cast<const floatx4*>(bs + pair * 16 + quad * 4);
            ushort4 u;
            unsigned short us[4];
#pragma unroll
            for (int r = 0; r < 4; ++r) {
                const float a1 = acc[pair][nt][r] + bt4[r];
                const float a2 = acc[2 + pair][nt][r] + bs4[r];
                const float th = 1.f - __fdividef(2.f, __expf(2.f * a1) + 1.f);
                const float sg = __fdividef(1.f, 1.f + __expf(-a2));
                us[r] = f2bf(th * sg);
            }
            u.x = us[0]; u.y = us[1]; u.z = us[2]; u.w = us[3];
            const int cbase = pair * 16 + quad * 4;
            *reinterpret_cast<ushort4*>(&gtile[tloc * 32 + cbase]) = u;
            *reinterpret_cast<ushort4*>(Gt + (size_t)t * KTOT + layer * 32 + cbase) = u;
        }
    }

    __syncthreads();

    short8 ad[2];
#pragma unroll
    for (int mt = 0; mt < 2; ++mt)
        ad[mt] = *reinterpret_cast<const short8*>(Wdb + (size_t)(mt * 16 + l16) * 32 + quad * 8);

#pragma unroll
    for (int nt = 0; nt < 2; ++nt) {
        const int t = tbase + nt * 16 + l16;
        const int tloc = w * 32 + nt * 16 + l16;
        const short8 bg = *reinterpret_cast<const short8*>(&gtile[tloc * 32 + quad * 8]);
#pragma unroll
        for (int mt = 0; mt < 2; ++mt) {
            const floatx4 a2 = __builtin_amdgcn_mfma_f32_16x16x32_bf16(ad[mt], bg, vzero, 0, 0, 0);
            const int m = mt * 16 + quad * 4;
            const floatx4 bd4 = *reinterpret_cast<const floatx4*>(bd + m);
            const floatx4 xi = *reinterpret_cast<const floatx4*>(xin + (size_t)t * RD + m);
            floatx4 o;
            ushort4 ob;
            o[0] = a2[0] + bd4[0] + xi[0]; ob.x = f2bf(o[0]);
            o[1] = a2[1] + bd4[1] + xi[1]; ob.y = f2bf(o[1]);
            o[2] = a2[2] + bd4[2] + xi[2]; ob.z = f2bf(o[2]);
            o[3] = a2[3] + bd4[3] + xi[3]; ob.w = f2bf(o[3]);
            *reinterpret_cast<floatx4*>(xout + (size_t)t * RD + m) = o;
            *reinterpret_cast<ushort4*>(xoutb + (size_t)t * RD + m) = ob;
        }
    }
}

// ---------------- Wcomb ----------------
__global__ __launch_bounds__(256)
void k_wcomb(const float* __restrict__ Wp1, const float* __restrict__ Wskip,
             unsigned short* __restrict__ Wcomb)
{
    const int idx = blockIdx.x * 256 + threadIdx.x;
    if (idx >= SD * KTOT) return;
    const int m = idx / KTOT;
    const int k = idx % KTOT;
    const int l = k / RD;
    const int c = k % RD;
    const float* wp1r = Wp1 + (size_t)m * SD;
    const float* wsk = Wskip + (size_t)l * SD * RD + c;
    float acc = 0.f;
    for (int j = 0; j < SD; ++j) acc += wp1r[j] * wsk[(size_t)j * RD];
    Wcomb[idx] = f2bf(acc);
}

// ---------------- hbias ----------------
__global__ __launch_bounds__(512)
void k_hbias(const float* __restrict__ Wp1, const float* __restrict__ bp1,
             const float* __restrict__ bskip, float* __restrict__ hbias)
{
    __shared__ float sb[SD];
    const int tid = threadIdx.x;
    float s = 0.f;
    for (int l = 0; l < NL; ++l) s += bskip[l * SD + tid];
    sb[tid] = s;
    __syncthreads();
    float acc = bp1[tid];
    const float* r = Wp1 + (size_t)tid * SD;
    for (int j = 0; j < SD; ++j) acc += r[j] * sb[j];
    hbias[tid] = acc;
}

// ---------------- fp32 -> bf16 cast ----------------
__global__ __launch_bounds__(256)
void k_cvt(const float* __restrict__ src, unsigned short* __restrict__ dst, int n)
{
    const int i = blockIdx.x * 256 + threadIdx.x;
    if (i < n) dst[i] = f2bf(src[i]);
}

// ---------------- GEMM1: ht[t][m] = relu(hbias[m] + Wcomb@Gt) ----------------
// Dual-LDS, now DOUBLE-BUFFERED with counted vmcnt (T4): K-step k+1's 4
// global_load_lds stay in flight across the barriers while step k computes.
// Never drain vmcnt to 0 in the main loop. Chunk-permutation swizzle on BOTH
// A and B: slot (r,c) holds global chunk c ^ ((r>>1)&3); reader quad ^ ((l16>>1)&3).
__global__ __launch_bounds__(256)
void k_gemm1(const unsigned short* __restrict__ A,   // Wcomb [512][864] bf16
             const unsigned short* __restrict__ B,   // Gt [T][864] bf16
             const float* __restrict__ hbias,
             unsigned short* __restrict__ ht)        // [T][512] bf16
{
    __shared__ unsigned short ldsA[2][128 * 32];  // 16 KB
    __shared__ unsigned short ldsB[2][128 * 32];  // 16 KB
    const int tid = threadIdx.x;
    const int lane = tid & 63;
    const int w = tid >> 6;
    const int wm = w & 1;
    const int wn = w >> 1;
    const int quad = lane >> 4;
    const int l16 = lane & 15;

    const int g = blockIdx.x;
    const int m0 = ((g >> 3) & 3) * 128;
    const int n0 = ((g & 7) + 8 * (g >> 5)) * 128;

    const int r4 = lane >> 2;
    const int c4 = lane & 3;
    const int srcc = c4 ^ ((r4 >> 1) & 3);   // permuted global chunk
    const int swz = (l16 >> 1) & 3;          // reader-side key

    floatx4 acc[4][4];
    const floatx4 vzero = {0.f, 0.f, 0.f, 0.f};
#pragma unroll
    for (int mt = 0; mt < 4; ++mt)
#pragma unroll
        for (int nt = 0; nt < 4; ++nt) acc[mt][nt] = vzero;

    // per-wave staging base pointers (rows w*32 + c*16 + r4)
    const unsigned short* pA = A + (size_t)(m0 + r4) * KTOT + srcc * 8;
    const unsigned short* pB = B + (size_t)(n0 + r4) * KTOT + srcc * 8;

    // prologue: stage K-step 0 into buffer 0
#pragma unroll
    for (int c = 0; c < 2; ++c) {
        const int row = w * 32 + c * 16;
        gload_lds16(pA + (size_t)row * KTOT, &ldsA[0][row * 32]);
        gload_lds16(pB + (size_t)row * KTOT, &ldsB[0][row * 32]);
    }

    for (int kc = 0; kc < KTOT / 32; ++kc) {
        const int cur = kc & 1;
        if (kc + 1 < KTOT / 32) {
            const int k0n = (kc + 1) * 32;
#pragma unroll
            for (int c = 0; c < 2; ++c) {
                const int row = w * 32 + c * 16;
                gload_lds16(pA + (size_t)row * KTOT + k0n, &ldsA[cur ^ 1][row * 32]);
                gload_lds16(pB + (size_t)row * KTOT + k0n, &ldsB[cur ^ 1][row * 32]);
            }
            // wait only for K-step kc's 4 loads; keep kc+1's 4 in flight
            asm volatile("s_waitcnt vmcnt(4)" ::: "memory");
        } else {
            asm volatile("s_waitcnt vmcnt(0)" ::: "memory");
        }
        __builtin_amdgcn_s_barrier();
        asm volatile("" ::: "memory");

        short8 afr[4], bfr[4];
#pragma unroll
        for (int mt = 0; mt < 4; ++mt)
            afr[mt] = *reinterpret_cast<const short8*>(
                &ldsA[cur][(wm * 64 + mt * 16 + l16) * 32 + (quad ^ swz) * 8]);
#pragma unroll
        for (int nt = 0; nt < 4; ++nt)
            bfr[nt] = *reinterpret_cast<const short8*>(
                &ldsB[cur][(wn * 64 + nt * 16 + l16) * 32 + (quad ^ swz) * 8]);
#pragma unroll
        for (int mt = 0; mt < 4; ++mt)
#pragma unroll
            for (int nt = 0; nt < 4; ++nt)
                acc[mt][nt] = __builtin_amdgcn_mfma_f32_16x16x32_bf16(afr[mt], bfr[nt], acc[mt][nt], 0, 0, 0);

        // all my LDS reads must be complete before anyone overwrites buf[cur]
        asm volatile("s_waitcnt lgkmcnt(0)" ::: "memory");
        __builtin_amdgcn_s_barrier();
    }

#pragma unroll
    for (int mt = 0; mt < 4; ++mt) {
        const int m = m0 + wm * 64 + mt * 16 + quad * 4;
        const floatx4 hb = *reinterpret_cast<const floatx4*>(hbias + m);
#pragma unroll
        for (int nt = 0; nt < 4; ++nt) {
            const int t = n0 + wn * 64 + nt * 16 + l16;
            ushort4 st;
            float v;
            v = acc[mt][nt][0] + hb[0]; st.x = f2bf(v > 0.f ? v : 0.f);
            v = acc[mt][nt][1] + hb[1]; st.y = f2bf(v > 0.f ? v : 0.f);
            v = acc[mt][nt][2] + hb[2]; st.z = f2bf(v > 0.f ? v : 0.f);
            v = acc[mt][nt][3] + hb[3]; st.w = f2bf(v > 0.f ? v : 0.f);
            *reinterpret_cast<ushort4*>(ht + (size_t)t * SD + m) = st;
        }
    }
}

// ---------------- GEMM2 + fused log_softmax, LDS-staged B ----------------
// Same counted-vmcnt double-buffer: B's gload_lds for step k+1 stays in
// flight (vmcnt(1)) while step k computes. A frags issued BEFORE the DMA so
// the compiler's afr wait (vmcnt(1)) doesn't drain the pipeline.
__global__ __launch_bounds__(256)
void k_gemm2_lsm(const unsigned short* __restrict__ A,  // Wp2b [256][512] bf16
                 const unsigned short* __restrict__ B,  // ht [T][512] bf16
                 const float* __restrict__ bp2,
                 float* __restrict__ out)               // [256][T] fp32
{
    __shared__ unsigned short ldsB[2][64 * 32];  // 8 KB
    __shared__ float redmax[4 * 16 * 16];
    __shared__ float redsum[4 * 16 * 16];
    const int tid = threadIdx.x;
    const int lane = tid & 63;
    const int w = tid >> 6;   // 0..3 = m-slice
    const int quad = lane >> 4;
    const int l16 = lane & 15;
    const int m0 = w * 64;
    const int n0 = blockIdx.x * 64;

    const int r4 = lane >> 2;
    const int c4 = lane & 3;
    const int srcc = c4 ^ ((r4 >> 1) & 3);
    const int swz = (l16 >> 1) & 3;

    const unsigned short* ab[4];
#pragma unroll
    for (int mt = 0; mt < 4; ++mt)
        ab[mt] = A + (size_t)(m0 + mt * 16 + l16) * SD + quad * 8;

    const unsigned short* pB = B + (size_t)(n0 + w * 16 + r4) * SD + srcc * 8;

    floatx4 acc[4][4];
    const floatx4 vzero = {0.f, 0.f, 0.f, 0.f};
#pragma unroll
    for (int mt = 0; mt < 4; ++mt)
#pragma unroll
        for (int nt = 0; nt < 4; ++nt) acc[mt][nt] = vzero;

    // prologue: stage K-step 0 into buffer 0
    gload_lds16(pB, &ldsB[0][(w * 16) * 32]);

    for (int kc = 0; kc < SD / 32; ++kc) {
        const int cur = kc & 1;
        const int k0 = kc * 32;

        short8 afr[4];
#pragma unroll
        for (int mt = 0; mt < 4; ++mt)
            afr[mt] = *reinterpret_cast<const short8*>(ab[mt] + k0);
        asm volatile("" ::: "memory");   // pin: afr loads issue before the DMA

        if (kc + 1 < SD / 32) {
            gload_lds16(pB + (kc + 1) * 32, &ldsB[cur ^ 1][(w * 16) * 32]);
            // newest outstanding = BDMA(kc+1); everything older (afr(kc),
            // BDMA(kc)) must be done
            asm volatile("s_waitcnt vmcnt(1)" ::: "memory");
        } else {
            asm volatile("s_waitcnt vmcnt(0)" ::: "memory");
        }
        __builtin_amdgcn_s_barrier();
        asm volatile("" ::: "memory");

        short8 bfr[4];
#pragma unroll
        for (int nt = 0; nt < 4; ++nt)
            bfr[nt] = *reinterpret_cast<const short8*>(
                &ldsB[cur][(nt * 16 + l16) * 32 + (quad ^ swz) * 8]);
#pragma unroll
        for (int mt = 0; mt < 4; ++mt)
#pragma unroll
            for (int nt = 0; nt < 4; ++nt)
                acc[mt][nt] = __builtin_amdgcn_mfma_f32_16x16x32_bf16(
                    afr[mt], bfr[nt], acc[mt][nt], 0, 0, 0);

        asm volatile("s_waitcnt lgkmcnt(0)" ::: "memory");
        __builtin_amdgcn_s_barrier();
    }

#pragma unroll
    for (int mt = 0; mt < 4; ++mt) {
        const int mb = m0 + mt * 16 + quad * 4;
        const floatx4 bz = *reinterpret_cast<const floatx4*>(bp2 + mb);
#pragma unroll
        for (int nt = 0; nt < 4; ++nt)
#pragma unroll
            for (int j = 0; j < 4; ++j) acc[mt][nt][j] += bz[j];
    }

#pragma unroll
    for (int nt = 0; nt < 4; ++nt) {
        float lm = -1e30f;
#pragma unroll
        for (int mt = 0; mt < 4; ++mt)
#pragma unroll
            for (int j = 0; j < 4; ++j) lm = fmaxf(lm, acc[mt][nt][j]);
        redmax[nt * 256 + l16 * 16 + w * 4 + quad] = lm;
    }
    __syncthreads();

    float lse[4];
#pragma unroll
    for (int nt = 0; nt < 4; ++nt) {
        float gm = -1e30f;
#pragma unroll
        for (int i = 0; i < 16; ++i) gm = fmaxf(gm, redmax[nt * 256 + l16 * 16 + i]);
        float ls = 0.f;
#pragma unroll
        for (int mt = 0; mt < 4; ++mt)
#pragma unroll
            for (int j = 0; j < 4; ++j) ls += __expf(acc[mt][nt][j] - gm);
        redsum[nt * 256 + l16 * 16 + w * 4 + quad] = ls;
        lse[nt] = gm;
    }
    __syncthreads();

#pragma unroll
    for (int nt = 0; nt < 4; ++nt) {
        float tot = 0.f;
#pragma unroll
        for (int i = 0; i < 16; ++i) tot += redsum[nt * 256 + l16 * 16 + i];
        lse[nt] = lse[nt] + __logf(tot);
    }

#pragma unroll
    for (int mt = 0; mt < 4; ++mt) {
        const int mb = m0 + mt * 16 + quad * 4;
#pragma unroll
        for (int nt = 0; nt < 4; ++nt) {
            const int t = n0 + nt * 16 + l16;
#pragma unroll
            for (int j = 0; j < 4; ++j)
                out[(size_t)(mb + j) * T_LEN + t] = acc[mt][nt][j] - lse[nt];
        }
    }
}

extern "C" void kernel_launch(void* const* d_in, const int* in_sizes, int n_in,
                              void* d_out, int out_size, void* d_ws, size_t ws_size,
                              hipStream_t stream)
{
    (void)in_sizes; (void)n_in; (void)out_size; (void)ws_size;
    const float* x     = (const float*)d_in[0];
    const float* Wc    = (const float*)d_in[1];
    const float* bc    = (const float*)d_in[2];
    const float* Wt    = (const float*)d_in[3];
    const float* bt    = (const float*)d_in[4];
    const float* Ws    = (const float*)d_in[5];
    const float* bs    = (const float*)d_in[6];
    const float* Wskip = (const float*)d_in[7];
    const float* bskip = (const float*)d_in[8];
    const float* Wd    = (const float*)d_in[9];
    const float* bd    = (const float*)d_in[10];
    const float* Wp1   = (const float*)d_in[11];
    const float* bp1   = (const float*)d_in[12];
    const float* Wp2   = (const float*)d_in[13];
    const float* bp2   = (const float*)d_in[14];
    float* out = (float*)d_out;

    char* p = (char*)d_ws;
    unsigned short* Gt = (unsigned short*)p;    p += (size_t)T_LEN * KTOT * 2;   // 226.5 MB
    unsigned short* ht = (unsigned short*)p;    p += (size_t)T_LEN * SD * 2;     // 134 MB
    unsigned short* Wcomb = (unsigned short*)p; p += (size_t)SD * KTOT * 2;
    unsigned short* Wp2b = (unsigned short*)p;  p += (size_t)QD * SD * 2;
    unsigned short* Wg = (unsigned short*)p;    p += (size_t)NL * 64 * 96 * 2;
    unsigned short* Wdb = (unsigned short*)p;   p += (size_t)NL * RD * RD * 2;
    float* hbias = (float*)p;                   p += (size_t)SD * 4;

    // x buffers alias the ht region (dead before gemm1 writes ht)
    char* q = (char*)ht;
    float* xa = (float*)q;                      q += (size_t)T_LEN * RD * 4;
    float* xb = (float*)q;                      q += (size_t)T_LEN * RD * 4;
    unsigned short* xba = (unsigned short*)q;   q += (size_t)T_LEN * RD * 2;
    unsigned short* xbb = (unsigned short*)q;   q += (size_t)T_LEN * RD * 2;

    k_wcomb<<<(SD * KTOT + 255) / 256, 256, 0, stream>>>(Wp1, Wskip, Wcomb);
    k_hbias<<<1, 512, 0, stream>>>(Wp1, bp1, bskip, hbias);
    k_cvt<<<(QD * SD + 255) / 256, 256, 0, stream>>>(Wp2, Wp2b, QD * SD);
    {
        const int nprep = NL * 64 * 96 + NL * RD * RD;
        k_wprep<<<(nprep + 255) / 256, 256, 0, stream>>>(Wt, Ws, Wd, Wg, Wdb);
    }
    k_conv_init<<<T_LEN / 256, 256, 0, stream>>>(x, Wc, bc, xa, xba);

    static const int dil[NL] = {1, 2, 4, 8, 16, 32, 64, 128, 256,
                                1, 2, 4, 8, 16, 32, 64, 128, 256,
                                1, 2, 4, 8, 16, 32, 64, 128, 256};
    const float* cur = xa;
    const unsigned short* curb = xba;
    float* nxt = xb;
    unsigned short* nxtb = xbb;
    for (int i = 0; i < NL; ++i) {
        k_layer_mfma<<<T_LEN / 128, 256, 0, stream>>>(
            cur, curb, nxt, nxtb, Gt,
            Wg + (size_t)i * 64 * 96,
            Wdb + (size_t)i * RD * RD,
            bt + (size_t)i * RD,
            bs + (size_t)i * RD,
            bd + (size_t)i * RD,
            dil[i], i);
        float* tf = (float*)cur; cur = nxt; nxt = tf;
        unsigned short* tb = (unsigned short*)curb; curb = nxtb; nxtb = tb;
    }

    k_gemm1<<<4 * (T_LEN / 128), 256, 0, stream>>>(Wcomb, Gt, hbias, ht);
    k_gemm2_lsm<<<T_LEN / 64, 256, 0, stream>>>(Wp2b, ht, bp2, out);
}

// Round 2
// 1028.968 us; speedup vs baseline: 1.0614x; 1.0614x over previous
//
#include <hip/hip_runtime.h>

#define T_LEN 131072
#define RD 32
#define SD 512
#define QD 256
#define NL 27
#define KTOT (NL * RD)   // 864

typedef __attribute__((ext_vector_type(8))) short short8;
typedef __attribute__((ext_vector_type(4))) float floatx4;

__device__ __forceinline__ unsigned short f2bf(float f) {
    union { float f; unsigned int i; } v; v.f = f;
    unsigned int r = v.i + 0x7fffu + ((v.i >> 16) & 1u);  // RNE
    return (unsigned short)(r >> 16);
}

__device__ __forceinline__ void gload_lds16(const void* g, void* l) {
    __builtin_amdgcn_global_load_lds(
        (const __attribute__((address_space(1))) unsigned int*)g,
        (__attribute__((address_space(3))) unsigned int*)l, 16, 0, 0);
}

// ---------------- initial conv: [1,T] -> [T][32] fp32 ----------------
__global__ __launch_bounds__(256)
void k_conv_init(const float* __restrict__ x, const float* __restrict__ Wc,
                 const float* __restrict__ bc, float* __restrict__ xout)
{
    const int t = blockIdx.x * 256 + threadIdx.x;
    const float xm = (t > 0) ? x[t - 1] : 0.f;
    const float x0 = x[t];
    const float xp = (t < T_LEN - 1) ? x[t + 1] : 0.f;
    float* row = xout + (size_t)t * RD;
#pragma unroll
    for (int o = 0; o < RD; ++o) {
        row[o] = bc[o] + Wc[o * 3 + 0] * xm + Wc[o * 3 + 1] * x0 + Wc[o * 3 + 2] * xp;
    }
}

// ---------------- weight prep ----------------
__global__ __launch_bounds__(256)
void k_wprep(const float* __restrict__ Wt, const float* __restrict__ Ws,
             const float* __restrict__ Wd,
             unsigned short* __restrict__ Wg, unsigned short* __restrict__ Wdb)
{
    const int idx = blockIdx.x * 256 + threadIdx.x;
    const int n1 = NL * 64 * 96;
    const int n2 = NL * RD * RD;
    if (idx < n1) {
        const int l = idx / (64 * 96);
        const int rem = idx % (64 * 96);
        const int m = rem / 96;
        const int k = rem % 96;
        const int j = k / 32;
        const int c = k % 32;
        float v;
        if (m < 32) v = Wt[(((size_t)l * RD + m) * RD + c) * 3 + j];
        else        v = Ws[(((size_t)l * RD + (m - 32)) * RD + c) * 3 + j];
        Wg[idx] = f2bf(v);
    } else if (idx < n1 + n2) {
        const int i2 = idx - n1;
        Wdb[i2] = f2bf(Wd[i2]);
    }
}

// ---------------- one residual layer via MFMA, 128 t per block ----------------
// x kept ONLY in fp32; bf16 MFMA operand built in-register (f2bf, identical
// numerics to the old stored-bf16 path). Gt written layer-major [NL][T][32]
// so each layer's store region is contiguous (coalesced lines, and gemm1's
// B-tile DMA becomes fully contiguous).
__global__ __launch_bounds__(256)
void k_layer_mfma(const float* __restrict__ xin,
                  float* __restrict__ xout,
                  unsigned short* __restrict__ Gt,      // [NL][T][32]
                  const unsigned short* __restrict__ Wg,   // [64][96] bf16
                  const unsigned short* __restrict__ Wdb,  // [32][32] bf16
                  const float* __restrict__ bt, const float* __restrict__ bs,
                  const float* __restrict__ bd, int d, int layer)
{
    __shared__ unsigned short gtile[128 * 32];  // 8 KB
    const int tid = threadIdx.x;
    const int lane = tid & 63;
    const int w = tid >> 6;
    const int quad = lane >> 4;
    const int l16 = lane & 15;
    const int tbase = blockIdx.x * 128 + w * 32;

    short8 afr[3][4];
#pragma unroll
    for (int j = 0; j < 3; ++j)
#pragma unroll
        for (int mt = 0; mt < 4; ++mt)
            afr[j][mt] = *reinterpret_cast<const short8*>(
                Wg + (size_t)(mt * 16 + l16) * 96 + j * 32 + quad * 8);

    floatx4 acc[4][2];
    const floatx4 vzero = {0.f, 0.f, 0.f, 0.f};
#pragma unroll
    for (int mt = 0; mt < 4; ++mt)
#pragma unroll
        for (int nt = 0; nt < 2; ++nt) acc[mt][nt] = vzero;

#pragma unroll
    for (int nt = 0; nt < 2; ++nt) {
        const int t = tbase + nt * 16 + l16;
#pragma unroll
        for (int j = 0; j < 3; ++j) {
            const int tt = t + (j - 1) * d;
            short8 b;
            if (tt >= 0 && tt < T_LEN) {
                const float* src = xin + (size_t)tt * RD + quad * 8;
                const floatx4 f0 = *reinterpret_cast<const floatx4*>(src);
                const floatx4 f1 = *reinterpret_cast<const floatx4*>(src + 4);
#pragma unroll
                for (int i = 0; i < 4; ++i) {
                    b[i] = (short)f2bf(f0[i]);
                    b[4 + i] = (short)f2bf(f1[i]);
                }
            } else {
#pragma unroll
                for (int i = 0; i < 8; ++i) b[i] = 0;
            }
#pragma unroll
            for (int mt = 0; mt < 4; ++mt)
                acc[mt][nt] = __builtin_amdgcn_mfma_f32_16x16x32_bf16(afr[j][mt], b, acc[mt][nt], 0, 0, 0);
        }
    }

#pragma unroll
    for (int nt = 0; nt < 2; ++nt) {
        const int t = tbase + nt * 16 + l16;
        const int tloc = w * 32 + nt * 16 + l16;
#pragma unroll
        for (int pair = 0; pair < 2; ++pair) {
            const floatx4 bt4 = *reinterpret_cast<const floatx4*>(bt + pair * 16 + quad * 4);
            const floatx4 bs4 = *reinterpret_cast<const floatx4*>(bs + pair * 16 + quad * 4);
            ushort4 u;
            unsigned short us[4];
#pragma unroll
            for (int r = 0; r < 4; ++r) {
                const float a1 = acc[pair][nt][r] + bt4[r];
                const float a2 = acc[2 + pair][nt][r] + bs4[r];
                const float th = 1.f - __fdividef(2.f, __expf(2.f * a1) + 1.f);
                const float sg = __fdividef(1.f, 1.f + __expf(-a2));
                us[r] = f2bf(th * sg);
            }
            u.x = us[0]; u.y = us[1]; u.z = us[2]; u.w = us[3];
            const int cbase = pair * 16 + quad * 4;
            *reinterpret_cast<ushort4*>(&gtile[tloc * 32 + cbase]) = u;
            *reinterpret_cast<ushort4*>(
                Gt + ((size_t)layer * T_LEN + t) * RD + cbase) = u;
        }
    }

    __syncthreads();

    short8 ad[2];
#pragma unroll
    for (int mt = 0; mt < 2; ++mt)
        ad[mt] = *reinterpret_cast<const short8*>(Wdb + (size_t)(mt * 16 + l16) * 32 + quad * 8);

#pragma unroll
    for (int nt = 0; nt < 2; ++nt) {
        const int t = tbase + nt * 16 + l16;
        const int tloc = w * 32 + nt * 16 + l16;
        const short8 bg = *reinterpret_cast<const short8*>(&gtile[tloc * 32 + quad * 8]);
#pragma unroll
        for (int mt = 0; mt < 2; ++mt) {
            const floatx4 a2 = __builtin_amdgcn_mfma_f32_16x16x32_bf16(ad[mt], bg, vzero, 0, 0, 0);
            const int m = mt * 16 + quad * 4;
            const floatx4 bd4 = *reinterpret_cast<const floatx4*>(bd + m);
            const floatx4 xi = *reinterpret_cast<const floatx4*>(xin + (size_t)t * RD + m);
            floatx4 o;
            o[0] = a2[0] + bd4[0] + xi[0];
            o[1] = a2[1] + bd4[1] + xi[1];
            o[2] = a2[2] + bd4[2] + xi[2];
            o[3] = a2[3] + bd4[3] + xi[3];
            *reinterpret_cast<floatx4*>(xout + (size_t)t * RD + m) = o;
        }
    }
}

// ---------------- Wcomb (chunk-major [27][512][32]) ----------------
__global__ __launch_bounds__(256)
void k_wcomb(const float* __restrict__ Wp1, const float* __restrict__ Wskip,
             unsigned short* __restrict__ Wcomb)
{
    const int idx = blockIdx.x * 256 + threadIdx.x;
    if (idx >= SD * KTOT) return;
    const int m = idx / KTOT;
    const int k = idx % KTOT;
    const int l = k / RD;
    const int c = k % RD;
    const float* wp1r = Wp1 + (size_t)m * SD;
    const float* wsk = Wskip + (size_t)l * SD * RD + c;
    float acc = 0.f;
    for (int j = 0; j < SD; ++j) acc += wp1r[j] * wsk[(size_t)j * RD];
    Wcomb[((size_t)l * SD + m) * RD + c] = f2bf(acc);
}

// ---------------- hbias ----------------
__global__ __launch_bounds__(512)
void k_hbias(const float* __restrict__ Wp1, const float* __restrict__ bp1,
             const float* __restrict__ bskip, float* __restrict__ hbias)
{
    __shared__ float sb[SD];
    const int tid = threadIdx.x;
    float s = 0.f;
    for (int l = 0; l < NL; ++l) s += bskip[l * SD + tid];
    sb[tid] = s;
    __syncthreads();
    float acc = bp1[tid];
    const float* r = Wp1 + (size_t)tid * SD;
    for (int j = 0; j < SD; ++j) acc += r[j] * sb[j];
    hbias[tid] = acc;
}

// ---------------- fp32 -> bf16 cast ----------------
__global__ __launch_bounds__(256)
void k_cvt(const float* __restrict__ src, unsigned short* __restrict__ dst, int n)
{
    const int i = blockIdx.x * 256 + threadIdx.x;
    if (i < n) dst[i] = f2bf(src[i]);
}

// ---------------- GEMM1: ht = relu(hbias + Wcomb@Gt) ----------------
// r0 structure (single-buffer, 2 barriers/step — known-good 220 µs shape).
// A chunk-major [27][512][32], B layer-major [27][T][32]: every
// global_load_lds covers 16 consecutive 64 B rows = one contiguous 1 KB DMA.
// ht written chunk-major [16][T][32] for gemm2.
__global__ __launch_bounds__(256)
void k_gemm1(const unsigned short* __restrict__ A,   // Wcomb [27][512][32]
             const unsigned short* __restrict__ B,   // Gt [27][T][32]
             const float* __restrict__ hbias,
             unsigned short* __restrict__ ht)        // [16][T][32]
{
    __shared__ unsigned short ldsA[128 * 32];  // 8 KB
    __shared__ unsigned short ldsB[128 * 32];  // 8 KB
    const int tid = threadIdx.x;
    const int lane = tid & 63;
    const int w = tid >> 6;
    const int wm = w & 1;
    const int wn = w >> 1;
    const int quad = lane >> 4;
    const int l16 = lane & 15;

    const int g = blockIdx.x;
    const int m0 = ((g >> 3) & 3) * 128;
    const int n0 = ((g & 7) + 8 * (g >> 5)) * 128;

    const int r4 = lane >> 2;
    const int c4 = lane & 3;
    const int srcc = c4 ^ ((r4 >> 1) & 3);   // permuted global chunk
    const int swz = (l16 >> 1) & 3;          // reader-side key

    floatx4 acc[4][4];
    const floatx4 vzero = {0.f, 0.f, 0.f, 0.f};
#pragma unroll
    for (int mt = 0; mt < 4; ++mt)
#pragma unroll
        for (int nt = 0; nt < 4; ++nt) acc[mt][nt] = vzero;

    const unsigned short* pA = A + (size_t)(m0 + r4) * RD + srcc * 8;
    const unsigned short* pB = B + (size_t)(n0 + r4) * RD + srcc * 8;

    for (int kc = 0; kc < KTOT / 32; ++kc) {
#pragma unroll
        for (int c = 0; c < 2; ++c) {
            const int row = w * 32 + c * 16;
            gload_lds16(pA + ((size_t)kc * SD + row) * RD, &ldsA[(size_t)row * 32]);
            gload_lds16(pB + ((size_t)kc * T_LEN + row) * RD, &ldsB[(size_t)row * 32]);
        }
        __syncthreads();

        short8 afr[4], bfr[4];
#pragma unroll
        for (int mt = 0; mt < 4; ++mt)
            afr[mt] = *reinterpret_cast<const short8*>(
                &ldsA[(wm * 64 + mt * 16 + l16) * 32 + (quad ^ swz) * 8]);
#pragma unroll
        for (int nt = 0; nt < 4; ++nt)
            bfr[nt] = *reinterpret_cast<const short8*>(
                &ldsB[(wn * 64 + nt * 16 + l16) * 32 + (quad ^ swz) * 8]);
#pragma unroll
        for (int mt = 0; mt < 4; ++mt)
#pragma unroll
            for (int nt = 0; nt < 4; ++nt)
                acc[mt][nt] = __builtin_amdgcn_mfma_f32_16x16x32_bf16(afr[mt], bfr[nt], acc[mt][nt], 0, 0, 0);
        __syncthreads();
    }

#pragma unroll
    for (int mt = 0; mt < 4; ++mt) {
        const int m = m0 + wm * 64 + mt * 16 + quad * 4;
        const floatx4 hb = *reinterpret_cast<const floatx4*>(hbias + m);
        const size_t chunkbase = (size_t)(m >> 5) * T_LEN;
        const int mc = m & 31;
#pragma unroll
        for (int nt = 0; nt < 4; ++nt) {
            const int t = n0 + wn * 64 + nt * 16 + l16;
            ushort4 st;
            float v;
            v = acc[mt][nt][0] + hb[0]; st.x = f2bf(v > 0.f ? v : 0.f);
            v = acc[mt][nt][1] + hb[1]; st.y = f2bf(v > 0.f ? v : 0.f);
            v = acc[mt][nt][2] + hb[2]; st.z = f2bf(v > 0.f ? v : 0.f);
            v = acc[mt][nt][3] + hb[3]; st.w = f2bf(v > 0.f ? v : 0.f);
            *reinterpret_cast<ushort4*>(ht + (chunkbase + t) * RD + mc) = st;
        }
    }
}

// ---------------- GEMM2 + fused log_softmax, LDS-staged B ----------------
// r0 structure; B = ht chunk-major [16][T][32] so the B DMA is contiguous.
__global__ __launch_bounds__(256)
void k_gemm2_lsm(const unsigned short* __restrict__ A,  // Wp2b [256][512] bf16
                 const unsigned short* __restrict__ B,  // ht [16][T][32] bf16
                 const float* __restrict__ bp2,
                 float* __restrict__ out)               // [256][T] fp32
{
    __shared__ unsigned short ldsB[64 * 32];  // 4 KB
    __shared__ float redmax[4 * 16 * 16];
    __shared__ float redsum[4 * 16 * 16];
    const int tid = threadIdx.x;
    const int lane = tid & 63;
    const int w = tid >> 6;   // 0..3 = m-slice
    const int quad = lane >> 4;
    const int l16 = lane & 15;
    const int m0 = w * 64;
    const int n0 = blockIdx.x * 64;

    const int r4 = lane >> 2;
    const int c4 = lane & 3;
    const int srcc = c4 ^ ((r4 >> 1) & 3);
    const int swz = (l16 >> 1) & 3;

    const unsigned short* ab[4];
#pragma unroll
    for (int mt = 0; mt < 4; ++mt)
        ab[mt] = A + (size_t)(m0 + mt * 16 + l16) * SD + quad * 8;

    const unsigned short* pB = B + (size_t)(n0 + w * 16 + r4) * RD + srcc * 8;

    floatx4 acc[4][4];
    const floatx4 vzero = {0.f, 0.f, 0.f, 0.f};
#pragma unroll
    for (int mt = 0; mt < 4; ++mt)
#pragma unroll
        for (int nt = 0; nt < 4; ++nt) acc[mt][nt] = vzero;

    for (int kc = 0; kc < SD / 32; ++kc) {
        const int k0 = kc * 32;
        gload_lds16(pB + (size_t)kc * T_LEN * RD, &ldsB[(size_t)(w * 16) * 32]);
        short8 afr[4];
#pragma unroll
        for (int mt = 0; mt < 4; ++mt)
            afr[mt] = *reinterpret_cast<const short8*>(ab[mt] + k0);
        __syncthreads();

        short8 bfr[4];
#pragma unroll
        for (int nt = 0; nt < 4; ++nt)
            bfr[nt] = *reinterpret_cast<const short8*>(
                &ldsB[(nt * 16 + l16) * 32 + (quad ^ swz) * 8]);
#pragma unroll
        for (int mt = 0; mt < 4; ++mt)
#pragma unroll
            for (int nt = 0; nt < 4; ++nt)
                acc[mt][nt] = __builtin_amdgcn_mfma_f32_16x16x32_bf16(
                    afr[mt], bfr[nt], acc[mt][nt], 0, 0, 0);
        __syncthreads();
    }

#pragma unroll
    for (int mt = 0; mt < 4; ++mt) {
        const int mb = m0 + mt * 16 + quad * 4;
        const floatx4 bz = *reinterpret_cast<const floatx4*>(bp2 + mb);
#pragma unroll
        for (int nt = 0; nt < 4; ++nt)
#pragma unroll
            for (int j = 0; j < 4; ++j) acc[mt][nt][j] += bz[j];
    }

#pragma unroll
    for (int nt = 0; nt < 4; ++nt) {
        float lm = -1e30f;
#pragma unroll
        for (int mt = 0; mt < 4; ++mt)
#pragma unroll
            for (int j = 0; j < 4; ++j) lm = fmaxf(lm, acc[mt][nt][j]);
        redmax[nt * 256 + l16 * 16 + w * 4 + quad] = lm;
    }
    __syncthreads();

    float lse[4];
#pragma unroll
    for (int nt = 0; nt < 4; ++nt) {
        float gm = -1e30f;
#pragma unroll
        for (int i = 0; i < 16; ++i) gm = fmaxf(gm, redmax[nt * 256 + l16 * 16 + i]);
        float ls = 0.f;
#pragma unroll
        for (int mt = 0; mt < 4; ++mt)
#pragma unroll
            for (int j = 0; j < 4; ++j) ls += __expf(acc[mt][nt][j] - gm);
        redsum[nt * 256 + l16 * 16 + w * 4 + quad] = ls;
        lse[nt] = gm;
    }
    __syncthreads();

#pragma unroll
    for (int nt = 0; nt < 4; ++nt) {
        float tot = 0.f;
#pragma unroll
        for (int i = 0; i < 16; ++i) tot += redsum[nt * 256 + l16 * 16 + i];
        lse[nt] = lse[nt] + __logf(tot);
    }

#pragma unroll
    for (int mt = 0; mt < 4; ++mt) {
        const int mb = m0 + mt * 16 + quad * 4;
#pragma unroll
        for (int nt = 0; nt < 4; ++nt) {
            const int t = n0 + nt * 16 + l16;
#pragma unroll
            for (int j = 0; j < 4; ++j)
                out[(size_t)(mb + j) * T_LEN + t] = acc[mt][nt][j] - lse[nt];
        }
    }
}

extern "C" void kernel_launch(void* const* d_in, const int* in_sizes, int n_in,
                              void* d_out, int out_size, void* d_ws, size_t ws_size,
                              hipStream_t stream)
{
    (void)in_sizes; (void)n_in; (void)out_size; (void)ws_size;
    const float* x     = (const float*)d_in[0];
    const float* Wc    = (const float*)d_in[1];
    const float* bc    = (const float*)d_in[2];
    const float* Wt    = (const float*)d_in[3];
    const float* bt    = (const float*)d_in[4];
    const float* Ws    = (const float*)d_in[5];
    const float* bs    = (const float*)d_in[6];
    const float* Wskip = (const float*)d_in[7];
    const float* bskip = (const float*)d_in[8];
    const float* Wd    = (const float*)d_in[9];
    const float* bd    = (const float*)d_in[10];
    const float* Wp1   = (const float*)d_in[11];
    const float* bp1   = (const float*)d_in[12];
    const float* Wp2   = (const float*)d_in[13];
    const float* bp2   = (const float*)d_in[14];
    float* out = (float*)d_out;

    char* p = (char*)d_ws;
    unsigned short* Gt = (unsigned short*)p;    p += (size_t)T_LEN * KTOT * 2;   // 226.5 MB, [27][T][32]
    unsigned short* ht = (unsigned short*)p;    p += (size_t)T_LEN * SD * 2;     // 134 MB, [16][T][32]
    unsigned short* Wcomb = (unsigned short*)p; p += (size_t)SD * KTOT * 2;
    unsigned short* Wp2b = (unsigned short*)p;  p += (size_t)QD * SD * 2;
    unsigned short* Wg = (unsigned short*)p;    p += (size_t)NL * 64 * 96 * 2;
    unsigned short* Wdb = (unsigned short*)p;   p += (size_t)NL * RD * RD * 2;
    float* hbias = (float*)p;                   p += (size_t)SD * 4;

    // x ping-pong buffers alias the ht region (dead before gemm1 writes ht)
    char* q = (char*)ht;
    float* xa = (float*)q;                      q += (size_t)T_LEN * RD * 4;
    float* xb = (float*)q;                      q += (size_t)T_LEN * RD * 4;

    k_wcomb<<<(SD * KTOT + 255) / 256, 256, 0, stream>>>(Wp1, Wskip, Wcomb);
    k_hbias<<<1, 512, 0, stream>>>(Wp1, bp1, bskip, hbias);
    k_cvt<<<(QD * SD + 255) / 256, 256, 0, stream>>>(Wp2, Wp2b, QD * SD);
    {
        const int nprep = NL * 64 * 96 + NL * RD * RD;
        k_wprep<<<(nprep + 255) / 256, 256, 0, stream>>>(Wt, Ws, Wd, Wg, Wdb);
    }
    k_conv_init<<<T_LEN / 256, 256, 0, stream>>>(x, Wc, bc, xa);

    static const int dil[NL] = {1, 2, 4, 8, 16, 32, 64, 128, 256,
                                1, 2, 4, 8, 16, 32, 64, 128, 256,
                                1, 2, 4, 8, 16, 32, 64, 128, 256};
    const float* cur = xa;
    float* nxt = xb;
    for (int i = 0; i < NL; ++i) {
        k_layer_mfma<<<T_LEN / 128, 256, 0, stream>>>(
            cur, nxt, Gt,
            Wg + (size_t)i * 64 * 96,
            Wdb + (size_t)i * RD * RD,
            bt + (size_t)i * RD,
            bs + (size_t)i * RD,
            bd + (size_t)i * RD,
            dil[i], i);
        float* tf = (float*)cur; cur = nxt; nxt = tf;
    }

    k_gemm1<<<4 * (T_LEN / 128), 256, 0, stream>>>(Wcomb, Gt, hbias, ht);
    k_gemm2_lsm<<<T_LEN / 64, 256, 0, stream>>>(Wp2b, ht, bp2, out);
}